// Round 8
// baseline (146.079 us; speedup 1.0000x reference)
//
#include <hip/hip_runtime.h>
#include <hip/hip_bf16.h>
#include <math.h>

#define ICH   3
#define OCH   16
#define ID    18
#define IH    34
#define IW    34
#define OD    16
#define OH    32
#define OW    32
#define NB    128
#define SPATIAL  (OD * OH * OW)     // 16384 per (b,c)
#define EPSV     1e-5f
#define PLANE    (IH * IW)          // 1156
#define XS_ELEMS (9 * PLANE)        // 10404 fp16 staged per block

typedef __fp16 fp16x2 __attribute__((ext_vector_type(2)));
typedef _Float16 half8v __attribute__((ext_vector_type(8)));
typedef float f32x4 __attribute__((ext_vector_type(4)));

// Budget (R3-R7): conv VALU busy ~40us = non-MFMA MAC floor (4 formulations
// agree); norm 11us = BW roofline; fixed harness ~65us. MfmaUtil has been
// 0.0 all session -> this round moves conv MACs to the matrix pipe.
// mfma_f32_16x16x32_f16: M=16 w-positions, N=16 channels, K=3x(27 taps pad
// 32). A/B slot-symmetric tap packing (correct for ANY hw k-permutation);
// C/D map col=lane&15 row=(lane>>4)*4+reg is HW-verified. Gathers are
// ds_read_u16 with compile-time immediate offsets off 8 per-lane bases.

// Pre-pass: wB[ic][c][taup] fp16, taup 0..31, zero-padded taus 27..31.
// tau = kd*9 + kh*3 + kw matches cw (OIDHW) inner layout directly.
__global__ void transpose_w_kernel(const float* __restrict__ cw,
                                   unsigned short* __restrict__ wB) {
    const int i = blockIdx.x * 256 + threadIdx.x;   // 0..1535
    if (i < 3 * 16 * 32) {
        const int ic = i >> 9, rem = i & 511, c = rem >> 5, tp = rem & 31;
        const float f = (tp < 27) ? cw[c * 81 + ic * 27 + tp] : 0.0f;
        union { __fp16 h; unsigned short u; } uu;
        uu.h = (__fp16)f;
        wB[i] = uu.u;
    }
}

// ===== conv v14: MFMA conv. One (b,d) slice per block, 4 waves, wave wv
// owns rows 8wv..8wv+7; tile = (row, w-half), 16 tiles x 3 mfma each.
// Lane: channel=lane&15 (B col / D col), k-group=lane>>4. Per-lane A-gather
// bases computed once; all reads use immediate offsets (no per-tile VALU).
// Do NOT: occupancy pushes (R4), pk_fma_f16 (R6), channel-last y (R2),
// XCD remap+reg pipeline (R7: no wall-clock gain).
__global__ __launch_bounds__(256, 2) void conv_stats_kernel(
    const float* __restrict__ x, const unsigned short* __restrict__ wB,
    const float* __restrict__ cb, const float* __restrict__ mult,
    unsigned short* __restrict__ y, float* __restrict__ stats)
{
    __shared__ __fp16 xs[XS_ELEMS];          // [9][34][34] flat, 20808 B
    __shared__ float wsum[4][OCH], wsq[4][OCH];

    const int blk = blockIdx.x;
    const int b = blk >> 4;
    const int d = blk & 15;
    const int tid = threadIdx.x;

    // ---- stage 9 (ic,kd) planes fp32 -> fp16 LDS (coalesced dwords) ----
#pragma unroll
    for (int p = 0; p < 9; p++) {
        const int ic = p / 3, kd = p % 3;    // compile-time
        const float* plane = x + ((size_t)(b * ICH + ic) * ID + (d + kd)) * PLANE;
#pragma unroll
        for (int j0 = 0; j0 < 5; j0++) {
            const int j = j0 * 256 + tid;
            if (j < PLANE) xs[p * PLANE + j] = (__fp16)plane[j];
        }
    }

    const int lane = tid & 63;
    const int wv   = tid >> 6;      // wave id -> rows 8wv..8wv+7
    const int kg   = lane >> 4;     // k-group 0..3 (8 taps each)
    const int ml   = lane & 15;     // A row (w-pos) / B,D col (channel)

    // ---- B fragments: 8 contiguous fp16 per lane per ic ----
    half8v bfrag[3];
#pragma unroll
    for (int ic = 0; ic < 3; ic++) {
        union { uint4 u; half8v h; } bb;
        bb.u = *(const uint4*)(wB + (ic * 16 + ml) * 32 + kg * 8);
        bfrag[ic] = bb.h;
    }

    // ---- per-lane A gather base indices (elements; ic=0, th=0, hf=0) ----
    int aidx[8];
#pragma unroll
    for (int j = 0; j < 8; j++) {
        int tau = kg * 8 + j;
        if (tau > 26) tau = 26;              // pad slots: B weight = 0
        const int kd  = (tau * 57) >> 9;     // tau/9 for tau<32
        const int rem = tau - 9 * kd;
        const int kh  = (rem * 11) >> 5;     // rem/3 for rem<9
        const int kw  = rem - 3 * kh;
        aidx[j] = kd * PLANE + (kh + 8 * wv) * IW + ml + kw;
    }

    __syncthreads();

    f32x4 acc[8][2];
#pragma unroll
    for (int t = 0; t < 8; t++) {
        acc[t][0] = f32x4{0.f, 0.f, 0.f, 0.f};
        acc[t][1] = f32x4{0.f, 0.f, 0.f, 0.f};
    }

    // ---- 16 tiles x 3 mfma; gathers use compile-time immediate offsets ----
#pragma unroll
    for (int th = 0; th < 8; th++) {
#pragma unroll
        for (int hf = 0; hf < 2; hf++) {
#pragma unroll
            for (int ic = 0; ic < 3; ic++) {
                const int off = th * IW + hf * 16 + ic * 3 * PLANE;  // const
                const unsigned int g0 = *(const unsigned short*)&xs[aidx[0] + off];
                const unsigned int g1 = *(const unsigned short*)&xs[aidx[1] + off];
                const unsigned int g2 = *(const unsigned short*)&xs[aidx[2] + off];
                const unsigned int g3 = *(const unsigned short*)&xs[aidx[3] + off];
                const unsigned int g4 = *(const unsigned short*)&xs[aidx[4] + off];
                const unsigned int g5 = *(const unsigned short*)&xs[aidx[5] + off];
                const unsigned int g6 = *(const unsigned short*)&xs[aidx[6] + off];
                const unsigned int g7 = *(const unsigned short*)&xs[aidx[7] + off];
                union { unsigned int u[4]; half8v h; } af;
                af.u[0] = g0 | (g1 << 16);
                af.u[1] = g2 | (g3 << 16);
                af.u[2] = g4 | (g5 << 16);
                af.u[3] = g6 | (g7 << 16);
                acc[th][hf] = __builtin_amdgcn_mfma_f32_16x16x32_f16(
                    af.h, bfrag[ic], acc[th][hf], 0, 0, 0);
            }
        }
    }

    // ---- epilogue: bias+mult fold, stats, y store (channel-major) ----
    const float bv = cb[ml];
    const float mv = mult[ml];
    float ssum = 0.0f, ssq = 0.0f;
#pragma unroll
    for (int th = 0; th < 8; th++) {
#pragma unroll
        for (int hf = 0; hf < 2; hf++) {
            const f32x4 a = acc[th][hf];
            const float o0 = (a[0] + bv) * mv;
            const float o1 = (a[1] + bv) * mv;
            const float o2 = (a[2] + bv) * mv;
            const float o3 = (a[3] + bv) * mv;
            ssum += (o0 + o1) + (o2 + o3);
            ssq  += (o0 * o0 + o1 * o1) + (o2 * o2 + o3 * o3);
            const size_t yi = ((size_t)(b * OCH + ml) * OD + d) * (OH * OW)
                            + (size_t)(8 * wv + th) * OW + hf * 16 + kg * 4;
            union { fp16x2 h; unsigned int u; } p01, p23;
            p01.h = __builtin_amdgcn_cvt_pkrtz(o0, o1);
            p23.h = __builtin_amdgcn_cvt_pkrtz(o2, o3);
            uint2 pk; pk.x = p01.u; pk.y = p23.u;
            *(uint2*)&y[yi] = pk;
        }
    }

    // reduce lanes sharing a channel (lane, lane^16, lane^32, lane^48)
    ssum += __shfl_xor(ssum, 16); ssum += __shfl_xor(ssum, 32);
    ssq  += __shfl_xor(ssq, 16);  ssq  += __shfl_xor(ssq, 32);
    if (lane < 16) { wsum[wv][ml] = ssum; wsq[wv][ml] = ssq; }
    __syncthreads();
    if (tid < OCH) {
        float s = 0.0f, q = 0.0f;
#pragma unroll
        for (int k = 0; k < 4; k++) { s += wsum[k][tid]; q += wsq[k][tid]; }
        const int sbase = ((b * OD + d) * OCH + tid) * 2;
        stats[sbase + 0] = s;
        stats[sbase + 1] = q;
    }
}

// ===== per-(b,c) norm params: {A = rs*m, B = -mean*rs*m, L = -|m|, H = +|m|}
__global__ void params_kernel(const float* __restrict__ stats,
                              const float* __restrict__ mult,
                              float4* __restrict__ prm)
{
    const int i = blockIdx.x * 256 + threadIdx.x;   // (b,c) pair
    if (i < NB * OCH) {
        const int b = i >> 4, c = i & 15;
        float s = 0.0f, q = 0.0f;
        for (int dd = 0; dd < OD; dd++) {
            s += stats[((b * OD + dd) * OCH + c) * 2 + 0];
            q += stats[((b * OD + dd) * OCH + c) * 2 + 1];
        }
        const float mean = s * (1.0f / (float)SPATIAL);
        float var = q * (1.0f / (float)SPATIAL) - mean * mean;
        var = fmaxf(var, 0.0f);
        const float rs = rsqrtf(var + EPSV);
        const float m  = mult[c];
        float4 p;
        p.x = rs * m;             // A
        p.y = -mean * rs * m;     // B
        p.z = -fabsf(m);          // L
        p.w =  fabsf(m);          // H
        prm[i] = p;
    }
}

// ===== norm_max (R1 version, measured ~11us = BW roofline; do not touch).
__global__ __launch_bounds__(256, 4) void norm_max_kernel(
    const unsigned short* __restrict__ y, const float4* __restrict__ prm,
    float* __restrict__ out)
{
    const int blk = blockIdx.x;     // NB*8 = 1024
    const int b   = blk >> 3;
    const int seg = blk & 7;
    const int tid = threadIdx.x;

    const int s = seg * 2048 + tid * 8;                  // 8 positions
    const unsigned short* yb = y + (size_t)b * OCH * SPATIAL + s;

    uint4 v[OCH];
#pragma unroll
    for (int c = 0; c < OCH; c++) {
        v[c] = *(const uint4*)(yb + (size_t)c * SPATIAL);
    }

    const float4* pb = prm + b * OCH;

    float mx[8];
#pragma unroll
    for (int j = 0; j < 8; j++) mx[j] = -INFINITY;

#pragma unroll
    for (int c = 0; c < OCH; c++) {
        const float4 p = pb[c];          // wave-uniform addr
        const float A = p.x, Bv = p.y, L = p.z, H = p.w;
        union { uint4 u4; unsigned int u[4]; } vv; vv.u4 = v[c];
#pragma unroll
        for (int w = 0; w < 4; w++) {
            union { unsigned int u; __fp16 h[2]; } a; a.u = vv.u[w];
            float f0 = fmaf((float)a.h[0], A, Bv);
            float f1 = fmaf((float)a.h[1], A, Bv);
            f0 = fminf(fmaxf(f0, L), H);                 // v_med3_f32 idiom
            f1 = fminf(fmaxf(f1, L), H);
            mx[2 * w]     = fmaxf(mx[2 * w],     f0);
            mx[2 * w + 1] = fmaxf(mx[2 * w + 1], f1);
        }
    }

    float* ob = out + (size_t)b * SPATIAL + s;
    float4 o0, o1;
    o0.x = mx[0]; o0.y = mx[1]; o0.z = mx[2]; o0.w = mx[3];
    o1.x = mx[4]; o1.y = mx[5]; o1.z = mx[6]; o1.w = mx[7];
    *(float4*)ob       = o0;
    *(float4*)(ob + 4) = o1;
}

extern "C" void kernel_launch(void* const* d_in, const int* in_sizes, int n_in,
                              void* d_out, int out_size, void* d_ws, size_t ws_size,
                              hipStream_t stream) {
    const float* x    = (const float*)d_in[0];
    const float* cw   = (const float*)d_in[1];
    const float* cb   = (const float*)d_in[2];
    const float* mult = (const float*)d_in[3];
    float* out = (float*)d_out;

    // ws: y fp16 channel-major (64 MB) | stats partials (256 KB) | prm (8 KB) | wB (3 KB)
    unsigned short* y = (unsigned short*)d_ws;
    float* stats = (float*)((char*)d_ws + (size_t)NB * OCH * SPATIAL * sizeof(unsigned short));
    float4* prm  = (float4*)(stats + NB * OD * OCH * 2);
    unsigned short* wBp = (unsigned short*)(prm + NB * OCH);

    transpose_w_kernel<<<6, 256, 0, stream>>>(cw, wBp);
    conv_stats_kernel<<<NB * 16, 256, 0, stream>>>(x, wBp, cb, mult, y, stats);
    params_kernel<<<8, 256, 0, stream>>>(stats, mult, prm);
    norm_max_kernel<<<NB * 8, 256, 0, stream>>>(y, prm, out);
}